// Round 8
// baseline (1126.748 us; speedup 1.0000x reference)
//
#include <hip/hip_runtime.h>

#define T_STEPS 2000
#define NBATCH  256
#define HID     51
#define FEAT    49
#define ROWF4   784                         // 64 rows * 49 floats / 4
#define XTOT4   (NBATCH * T_STEPS * FEAT / 4)
#define PSTRIDE 5                           // preact tile row stride (dwords), odd => conflict-free

typedef _Float16 v2h __attribute__((ext_vector_type(2)));

__device__ __forceinline__ float rl(float v, int lane) {
    return __int_as_float(__builtin_amdgcn_readlane(__float_as_int(v), lane));
}
__device__ __forceinline__ int rli(int v, int lane) {
    return __builtin_amdgcn_readlane(v, lane);
}
__device__ __forceinline__ float sigmoidf_fast(float x) {
    return __builtin_amdgcn_rcpf(1.0f + __builtin_amdgcn_exp2f(-1.4426950408889634f * x));
}
__device__ __forceinline__ float tanhf_fast(float x) {
    return 1.0f - 2.0f * __builtin_amdgcn_rcpf(1.0f + __builtin_amdgcn_exp2f(2.8853900817779268f * x));
}
__device__ __forceinline__ int packh2(float lo, float hi) {
    v2h p = (v2h){(_Float16)lo, (_Float16)hi};
    return __builtin_bit_cast(int, p);
}
__device__ __forceinline__ float dot2(int w, int h, float acc) {
    return __builtin_amdgcn_fdot2(__builtin_bit_cast(v2h, w),
                                  __builtin_bit_cast(v2h, h), acc, false);
}
// LDS-only barrier: skip __syncthreads' vmcnt(0)/expcnt(0) drain.
__device__ __forceinline__ void bar_lds() {
    asm volatile("s_waitcnt lgkmcnt(0)" ::: "memory");
    __builtin_amdgcn_s_barrier();
    asm volatile("" ::: "memory");
}
__device__ __forceinline__ float row_dot(const float* row, const float* __restrict__ Wl) {
    float a0 = 0, a1 = 0, a2 = 0, a3 = 0, a4 = 0, a5 = 0, a6 = 0;
#pragma unroll
    for (int j = 0; j < FEAT; j += 7) {
        a0 = fmaf(row[j    ], Wl[j    ], a0);
        a1 = fmaf(row[j + 1], Wl[j + 1], a1);
        a2 = fmaf(row[j + 2], Wl[j + 2], a2);
        a3 = fmaf(row[j + 3], Wl[j + 3], a3);
        a4 = fmaf(row[j + 4], Wl[j + 4], a4);
        a5 = fmaf(row[j + 5], Wl[j + 5], a5);
        a6 = fmaf(row[j + 6], Wl[j + 6], a6);
    }
    return ((a0 + a1) + (a2 + a3)) + ((a4 + a5) + a6);
}

#define REP26(F) F(0) F(1) F(2) F(3) F(4) F(5) F(6) F(7) F(8) F(9) F(10) F(11) F(12) \
                 F(13) F(14) F(15) F(16) F(17) F(18) F(19) F(20) F(21) F(22) F(23) F(24) F(25)

// TWO samples per 512-thread block (waves 0-3 = sample A's 4 gates, waves
// 4-7 = sample B's). waves_per_eu(2): each SIMD hosts one A-wave + one
// B-wave, so one sample's LDS-round-trip/barrier stall hosts the other's
// dot-chain issue — guaranteed co-residency TLP (2 separate blocks/CU can't
// be forced). Everything else as round 7: per-gate wave, 26 packed-f16
// weight ints/lane, own-gate activation pre-exchange, lgkmcnt-only barriers,
// f16 DPP pair broadcast, fused x-projection, LDS-buffered output flush.
__global__ __attribute__((amdgpu_flat_work_group_size(512, 512), amdgpu_waves_per_eu(2)))
void rnn_kernel(
    const float* __restrict__ x,
    const float* __restrict__ Wl, const float* __restrict__ bl,
    const float* __restrict__ Wih1, const float* __restrict__ Whh1,
    const float* __restrict__ bih1, const float* __restrict__ bhh1,
    const float* __restrict__ Wih2, const float* __restrict__ Whh2,
    const float* __restrict__ bih2, const float* __restrict__ bhh2,
    const float* __restrict__ Wa, const float* __restrict__ ba,
    float* __restrict__ out)
{
    const int tid  = threadIdx.x;
    const int samp = tid >> 8;          // 0 / 1
    const int stid = tid & 255;         // thread id within sample
    const int wid  = stid >> 6;         // gate index
    const int lane = tid & 63;
    const int n    = blockIdx.x * 2 + samp;
    float* optr = out + (size_t)n * T_STEPS;
    const float4* x4 = (const float4*)x;
    const int sbase = n * (T_STEPS * FEAT / 4);

    __shared__ float xt_[2][64 * FEAT];           // 25088 B x-tiles
    __shared__ float pt[2][2][64 * PSTRIDE];      // 5120 B activated-gate exchange
    __shared__ float ob[2][64];                   // 512 B output buffers
    float4* t4s = (float4*)xt_[samp];

    // ---- weights: 26 packed f16 pairs per lane (sample-independent) ----
#define DECLW(j) int w_##j; int sh_##j;
    REP26(DECLW)
    {
        const float* srow;
        float msk;
        if (lane < HID) { srow = Whh1 + (wid * HID + lane) * HID; msk = 1.0f; }
        else            { srow = Wih2 + wid * HID; msk = (lane == HID) ? 1.0f : 0.0f; }
        const float wh2 = Whh2[wid] * ((lane == HID) ? 1.0f : 0.0f);
#define LOADW(j) { \
        float lo = srow[2*(j)] * msk; \
        float hi = (2*(j)+1 < HID) ? srow[2*(j)+1] * msk : wh2; \
        w_##j = packh2(lo, hi); \
        asm("" : "+v"(w_##j)); }
        REP26(LOADW)
    }

    float wx = 0.0f, b = 0.0f;
    if (lane < HID) {
        wx = Wih1[wid * HID + lane];
        b  = bih1[wid * HID + lane] + bhh1[wid * HID + lane];
    } else if (lane == HID) {
        b  = bih2[wid] + bhh2[wid];
    }
    const float wav = Wa[0], bav = ba[0];
    const float bl0 = bl[0];

#define INITS(j) sh_##j = 0;
    REP26(INITS)

    float c = 0.0f, h = 0.0f;

    // ---- x prefetch: 784 float4 per 64-step chunk over the sample's 256 threads ----
    float4 p0, p1, p2, p3;
#define PF(base) { \
        int g0_ = (base) + stid;       g0_ = g0_ < XTOT4 ? g0_ : (XTOT4 - 1); p0 = x4[g0_]; \
        int g1_ = (base) + 256 + stid; g1_ = g1_ < XTOT4 ? g1_ : (XTOT4 - 1); p1 = x4[g1_]; \
        int g2_ = (base) + 512 + stid; g2_ = g2_ < XTOT4 ? g2_ : (XTOT4 - 1); p2 = x4[g2_]; \
        if (stid < 16) { int g3_ = (base) + 768 + stid; g3_ = g3_ < XTOT4 ? g3_ : (XTOT4 - 1); p3 = x4[g3_]; } }
#define COMMIT { t4s[stid] = p0; t4s[stid + 256] = p1; t4s[stid + 512] = p2; \
                 if (stid < 16) t4s[stid + 768] = p3; }
#define ROWDOT(dst) { float d_ = row_dot(&xt_[samp][lane * FEAT], Wl); \
                      dst = fmaxf(d_ + bl0, 0.0f); }

    float xa, xb;
    PF(sbase)              COMMIT  bar_lds();  ROWDOT(xa)                // chunk 0
    PF(sbase + ROWF4)      bar_lds();  COMMIT  bar_lds();  ROWDOT(xb)    // chunk 1
    PF(sbase + 2 * ROWF4)                                                // chunk 2 in flight

    const int prow = lane * PSTRIDE;

#pragma unroll 1
    for (int t = 0; t <= T_STEPS; ++t) {
        if ((t & 63) == 0 && t > 0 && t < T_STEPS) {
            const int k = t >> 6;
            if (wid == 0) {                       // flush outputs (per-sample wave 0)
                int oi = 64 * (k - 1) - 1 + lane;
                float ov = ob[samp][lane];
                if (oi >= 0) optr[oi] = ov;
            }
            xa = xb;
            COMMIT                                 // chunk k+1 -> x-tile
            bar_lds();
            ROWDOT(xb)
            PF(sbase + (k + 2) * ROWF4)            // chunk k+2 in flight
        }
        float xt = rl(xa, t & 63);

        // ---- this wave's gate preact: 2 interleaved dot2 chains ----
        float aA = fmaf(wx, xt, b), aB = 0.0f;
#define DOT(j) { if ((j) & 1) aB = dot2(w_##j, sh_##j, aB); \
                 else         aA = dot2(w_##j, sh_##j, aA); }
        REP26(DOT)
        float a = aA + aB;

        // ---- own-gate activation BEFORE exchange (wave-uniform branch) ----
        float act = (wid == 2) ? tanhf_fast(a) : sigmoidf_fast(a);

        // ---- exchange activated gates: write own, barrier, read all 4 ----
        float* ptw = pt[samp][t & 1];
        ptw[prow + wid] = act;
        bar_lds();
        float ig = ptw[prow + 0];
        float fg = ptw[prow + 1];
        float gg = ptw[prow + 2];
        float og = ptw[prow + 3];

        // ---- short state update (redundant per wave; lane51 = LSTM2) ----
        c = fmaf(fg, c, ig * gg);
        h = og * tanhf_fast(c);
        if (t == 0 && lane >= HID) { c = 0.0f; h = 0.0f; }   // LSTM2 zero init (skew)

        if (wid == 0 && lane == HID && t > 0)                 // buffer output in LDS
            ob[samp][t & 63] = fmaf(h, wav, bav);

        // ---- h broadcast: f16 cvt + quad_perm neighbor + 26 readlanes ----
        int hz = (int)(unsigned)__builtin_bit_cast(unsigned short, (_Float16)h);
        int nb = __builtin_amdgcn_mov_dpp(hz, 0xB1, 0xF, 0xF, true);  // lane r <-> r^1
        int pair = hz | (nb << 16);          // even lane r: h[r] | h[r+1]<<16
#define BCAST(j) sh_##j = rli(pair, 2 * (j));
        REP26(BCAST)
    }

    // final output flush: out idx 1983..1999 live in slots 0..16
    if (wid == 0 && lane <= 16) optr[1983 + lane] = ob[samp][lane];
}

extern "C" void kernel_launch(void* const* d_in, const int* in_sizes, int n_in,
                              void* d_out, int out_size, void* d_ws, size_t ws_size,
                              hipStream_t stream) {
    const float* x    = (const float*)d_in[0];
    const float* Wl   = (const float*)d_in[1];
    const float* bl   = (const float*)d_in[2];
    const float* Wih1 = (const float*)d_in[3];
    const float* Whh1 = (const float*)d_in[4];
    const float* bih1 = (const float*)d_in[5];
    const float* bhh1 = (const float*)d_in[6];
    const float* Wih2 = (const float*)d_in[7];
    const float* Whh2 = (const float*)d_in[8];
    const float* bih2 = (const float*)d_in[9];
    const float* bhh2 = (const float*)d_in[10];
    const float* Wa   = (const float*)d_in[11];
    const float* ba   = (const float*)d_in[12];
    float* out = (float*)d_out;

    rnn_kernel<<<NBATCH / 2, 512, 0, stream>>>(x, Wl, bl, Wih1, Whh1, bih1, bhh1,
                                               Wih2, Whh2, bih2, bhh2, Wa, ba, out);
}